// Round 1
// baseline (330.883 us; speedup 1.0000x reference)
//
#include <hip/hip_runtime.h>
#include <hip/hip_fp16.h>

// Problem constants (from reference)
#define NN  100000   // nodes
#define FIN 128      // in features
#define HID 256      // hidden
#define NE  600000   // edges
#define FEPS 1e-12f

// ---------------------------------------------------------------------------
// Workspace layout (unchanged sizes):
//  Path A (~82.3 MB): Whh|Whl[256*256]h (=256KB, was Wt f32) | xh[NN*FIN]h |
//                     agg[NN*FIN]f | cnt|cur|off|col | g|r | bsum
// Evidence log:
//  - R5: bf16 FEATURES fail precision (1/||z|| amplification); fp16 OK
//    (absmax 0.0156 vs thr 0.0327). ws_size >= 31.1 MB.
//  - R6/R7/R8: occupancy lever exhausted at 32 waves/CU (291 us fused).
//  - R9: bytes not the limit. R10: divergent __shfl broken. R11: LDS fp32
//    atomics 3x slow (CAS codegen). R12: wider batch neutral (spills).
//  - R13: SPLIT WINS: barrier-free gather <50 us; gemm exposed: 265 us.
//  - R14: k2 unroll x4: VALUBusy 45->74%, 265->245 us. VALU-issue 181 us vs
//    83 us fp32-FMA floor. R15: sequential fmaf -> 1 v_fmac / MAC.
//  - R16 (this): fp32 FMA floor itself is the wall -> MFMA with exact
//    3-product fp16 emulation (Ah*Wh + Al*Wh + Ah*Wl, fp32 acc).
//    Error ~2^-21 rel => absmax stays at gather-fp16's 0.0156.
//    Predicted: gemm 245 -> ~55-80 us, total ~200 us.
// ---------------------------------------------------------------------------

typedef _Float16 f16x8 __attribute__((ext_vector_type(8)));
typedef float    f32x4 __attribute__((ext_vector_type(4)));

__device__ __forceinline__ int clampN(int v) {
    return ((unsigned)v < (unsigned)NN) ? v : 0;
}
// int64 vs int32 edge_index: little-endian int64 (<2^31) => odd words all 0.
__device__ __forceinline__ int detect4(const int* ei) {
    return ((ei[1] | ei[3] | ei[5] | ei[7]) == 0) ? 1 : 0;
}
__device__ __forceinline__ int ld_src(const int* ei, int e, int f) {
    return f ? ei[2 * e] : ei[e];
}
__device__ __forceinline__ int ld_dst(const int* ei, int e, int f) {
    return f ? ei[2 * (NE + e)] : ei[NE + e];
}

// ---------------------------------------------------------------------------
// Setup (fused): blocks [0,256) split weights to fp16 hi/lo in [j][k] layout;
// [256,256+ncv) x->fp16; [256+ncv, ...) in-degree count (cnt pre-zeroed).
// ---------------------------------------------------------------------------
__global__ __launch_bounds__(256) void setup_kernel(
    const int* __restrict__ ei,
    const float* __restrict__ x,
    const float* __restrict__ W1l, const float* __restrict__ W1r,
    __half* __restrict__ Whh, __half* __restrict__ Whl,
    __half* __restrict__ xh,
    int* __restrict__ cnt, int ncv)
{
    int b = blockIdx.x;
    int t = threadIdx.x;
    if (b < 256) {
        int j = b, k2 = t;   // row j of [W1l | W1r], contiguous k
        float v = (k2 < FIN) ? W1l[(size_t)j * FIN + k2]
                             : W1r[(size_t)j * FIN + (k2 - FIN)];
        __half h  = __float2half_rn(v);
        __half lo = __float2half_rn(v - __half2float(h));
        Whh[(size_t)j * (2 * FIN) + k2] = h;
        Whl[(size_t)j * (2 * FIN) + k2] = lo;
    } else if (b < 256 + ncv) {
        int idx = (b - 256) * 256 + t;           // 8-float group
        if (idx < NN * FIN / 8) {
            const float4* px = (const float4*)(x + (size_t)idx * 8);
            float4 v0 = px[0], v1 = px[1];
            __half2 h0 = __float22half2_rn(make_float2(v0.x, v0.y));
            __half2 h1 = __float22half2_rn(make_float2(v0.z, v0.w));
            __half2 h2 = __float22half2_rn(make_float2(v1.x, v1.y));
            __half2 h3 = __float22half2_rn(make_float2(v1.z, v1.w));
            uint4 u;
            u.x = __builtin_bit_cast(unsigned, h0);
            u.y = __builtin_bit_cast(unsigned, h1);
            u.z = __builtin_bit_cast(unsigned, h2);
            u.w = __builtin_bit_cast(unsigned, h3);
            ((uint4*)xh)[idx] = u;
        }
    } else {
        int e = (b - 256 - ncv) * 256 + t;
        if (e < NE) {
            int f = detect4(ei);
            atomicAdd(cnt + clampN(ld_dst(ei, e, f)), 1);
        }
    }
}

// 3-phase parallel exclusive scan of cnt[NN] -> off[NN+1]
__global__ __launch_bounds__(1024) void scan_a_kernel(
    const int* __restrict__ cnt, int* __restrict__ off, int* __restrict__ bsum)
{
    __shared__ int sm[1024];
    int t = threadIdx.x;
    int idx = blockIdx.x * 1024 + t;
    int v = (idx < NN) ? cnt[idx] : 0;
    sm[t] = v;
    __syncthreads();
    for (int d = 1; d < 1024; d <<= 1) {
        int w = (t >= d) ? sm[t - d] : 0;
        __syncthreads();
        sm[t] += w;
        __syncthreads();
    }
    if (idx < NN) off[idx] = sm[t] - v;
    if (t == 1023) bsum[blockIdx.x] = sm[1023];
}
__global__ __launch_bounds__(128) void scan_b_kernel(
    int* __restrict__ bsum, int* __restrict__ off, int nblocks)
{
    __shared__ int sm[128];
    int t = threadIdx.x;
    int v = (t < nblocks) ? bsum[t] : 0;
    sm[t] = v;
    __syncthreads();
    for (int d = 1; d < 128; d <<= 1) {
        int w = (t >= d) ? sm[t - d] : 0;
        __syncthreads();
        sm[t] += w;
        __syncthreads();
    }
    if (t < nblocks) bsum[t] = sm[t] - v;
    if (t == 0) off[NN] = NE;
}
__global__ __launch_bounds__(1024) void scan_c_kernel(
    const int* __restrict__ bsum, int* __restrict__ off)
{
    int idx = blockIdx.x * 1024 + threadIdx.x;
    if (idx < NN) off[idx] += bsum[blockIdx.x];
}

// place src ids into CSR slots
__global__ __launch_bounds__(256) void fill_kernel(
    const int* __restrict__ ei,
    const int* __restrict__ off, int* __restrict__ cur, int* __restrict__ col)
{
    int e = blockIdx.x * 256 + threadIdx.x;
    if (e >= NE) return;
    int f = detect4(ei);
    int src = clampN(ld_src(ei, e, f));
    int dst = clampN(ld_dst(ei, e, f));
    int p = atomicAdd(cur + dst, 1);
    col[off[dst] + p] = src;
}

// ---------------------------------------------------------------------------
// Path A, stage 1: barrier-free gather. 1 thread per (node, 16B fp16 chunk);
// 4-wide independent-load loop; mean written to global agg (fp32).
// ---------------------------------------------------------------------------
__global__ __launch_bounds__(256) void gather_kernel(
    const int* __restrict__ off, const int* __restrict__ col,
    const __half* __restrict__ xh, float* __restrict__ agg)
{
    int idx = blockIdx.x * 256 + threadIdx.x;
    if (idx >= NN * 16) return;
    int n     = idx >> 4;
    int ft    = idx & 15;
    int fbase = ft * 8;

    float a[8];
#pragma unroll
    for (int i = 0; i < 8; ++i) a[i] = 0.0f;

    int s0 = off[n], s1 = off[n + 1];
    int i = s0;
    for (; i + 3 < s1; i += 4) {            // 4 independent 16B loads
        int c0 = clampN(col[i]);
        int c1 = clampN(col[i + 1]);
        int c2 = clampN(col[i + 2]);
        int c3 = clampN(col[i + 3]);
        uint4 v0 = *(const uint4*)(xh + (size_t)c0 * FIN + fbase);
        uint4 v1 = *(const uint4*)(xh + (size_t)c1 * FIN + fbase);
        uint4 v2 = *(const uint4*)(xh + (size_t)c2 * FIN + fbase);
        uint4 v3 = *(const uint4*)(xh + (size_t)c3 * FIN + fbase);
#pragma unroll
        for (int u = 0; u < 4; ++u) {
            float2 f0 = __half22float2(__builtin_bit_cast(__half2, (&v0.x)[u]));
            float2 f1 = __half22float2(__builtin_bit_cast(__half2, (&v1.x)[u]));
            float2 f2 = __half22float2(__builtin_bit_cast(__half2, (&v2.x)[u]));
            float2 f3 = __half22float2(__builtin_bit_cast(__half2, (&v3.x)[u]));
            a[2 * u]     += (f0.x + f1.x) + (f2.x + f3.x);
            a[2 * u + 1] += (f0.y + f1.y) + (f2.y + f3.y);
        }
    }
    for (; i < s1; ++i) {
        int c0 = clampN(col[i]);
        uint4 v0 = *(const uint4*)(xh + (size_t)c0 * FIN + fbase);
#pragma unroll
        for (int u = 0; u < 4; ++u) {
            float2 f0 = __half22float2(__builtin_bit_cast(__half2, (&v0.x)[u]));
            a[2 * u]     += f0.x;
            a[2 * u + 1] += f0.y;
        }
    }
    float ic = 1.0f / fmaxf((float)(s1 - s0), 1.0f);
    float4* dst = (float4*)(agg + (size_t)n * FIN + fbase);
    dst[0] = make_float4(a[0] * ic, a[1] * ic, a[2] * ic, a[3] * ic);
    dst[1] = make_float4(a[4] * ic, a[5] * ic, a[6] * ic, a[7] * ic);
}

// ---------------------------------------------------------------------------
// fp32 -> fp16 hi/lo split, written to XOR-swizzled LDS tiles.
// Swizzle: 16B chunk c of row r lives at chunk (c ^ (r&7)) — read pattern
// (16 rows, same chunk) then aliases only 2-way (free, m136).
// ---------------------------------------------------------------------------
__device__ __forceinline__ void storeHiLo4(
    __half* Ah, __half* Al, int row, int k, float4 v)
{
    int addr = row * 256 + ((((k >> 3) ^ (row & 7)) << 3) | (k & 7));
    __half h0 = __float2half_rn(v.x), h1 = __float2half_rn(v.y);
    __half h2 = __float2half_rn(v.z), h3 = __float2half_rn(v.w);
    __half l0 = __float2half_rn(v.x - __half2float(h0));
    __half l1 = __float2half_rn(v.y - __half2float(h1));
    __half l2 = __float2half_rn(v.z - __half2float(h2));
    __half l3 = __float2half_rn(v.w - __half2float(h3));
    uint2 uh, ul;
    uh.x = __builtin_bit_cast(unsigned, __halves2half2(h0, h1));
    uh.y = __builtin_bit_cast(unsigned, __halves2half2(h2, h3));
    ul.x = __builtin_bit_cast(unsigned, __halves2half2(l0, l1));
    ul.y = __builtin_bit_cast(unsigned, __halves2half2(l2, l3));
    *(uint2*)(Ah + addr) = uh;
    *(uint2*)(Al + addr) = ul;
}

// ---------------------------------------------------------------------------
// Path A, stage 2: MFMA GEMM with exact fp32 emulation.
// Block: 512 thr (8 waves) = 64 nodes x 256 j, K=256.
// Wave (w): node-half (w&1)*32 (2 M-tiles), j-group (w>>1)*64 (4 N-tiles).
// Per K-step (32): 3 MFMAs/tile: Ah*Bh + Al*Bh + Ah*Bl  (fp32 acc).
// A hi/lo from LDS (ds_read_b128, swizzled); B hi/lo fp16 from global
// (L2-resident 256KB working set, reused 2x per wave via 2 M-tiles).
// C layout (m89-verified): col=lane&15 (j), row=(lane>>4)*4+reg (node).
// ---------------------------------------------------------------------------
__global__ __launch_bounds__(512, 4) void gemm_mfma_kernel(
    const float* __restrict__ agg, const float* __restrict__ x,
    const __half* __restrict__ Whh, const __half* __restrict__ Whl,
    const float* __restrict__ b1,
    const float* __restrict__ W2l, const float* __restrict__ W2r,
    float* __restrict__ g, float* __restrict__ r)
{
    __shared__ __half Ah[64 * 256];   // 32 KB
    __shared__ __half Al[64 * 256];   // 32 KB

    const int t  = threadIdx.x;
    const int nb = blockIdx.x * 64;

    // ---- stage A: coalesced float4 streams -> hi/lo fp16 swizzled LDS ----
    {
        const float4* aggF = (const float4*)agg;
        const float4* xF   = (const float4*)x;
        const float4 z4 = make_float4(0.f, 0.f, 0.f, 0.f);
#pragma unroll
        for (int i = 0; i < 4; ++i) {
            int idx   = i * 512 + t;        // 0..2047 = 64 rows x 32 f4
            int n_loc = idx >> 5;
            int kq    = idx & 31;
            int n     = nb + n_loc;
            bool valid = (n < NN);
            size_t base = (size_t)(valid ? n : 0) * 32 + kq;
            float4 va = aggF[base];
            float4 vx = xF[base];
            if (!valid) { va = z4; vx = z4; }
            storeHiLo4(Ah, Al, n_loc, kq * 4, va);          // k in [0,128)
            storeHiLo4(Ah, Al, n_loc, FIN + kq * 4, vx);    // k in [128,256)
        }
    }
    __syncthreads();

    const int l     = t & 63;
    const int w     = t >> 6;          // wave 0..7
    const int ln    = l & 15;
    const int kg    = l >> 4;          // 0..3 (K sub-chunk of the frag)
    const int mrow0 = (w & 1) * 32;    // node offset within tile
    const int jb    = (w >> 1) * 64;   // j offset

    f32x4 acc[2][4];
#pragma unroll
    for (int mt = 0; mt < 2; ++mt)
#pragma unroll
        for (int jt = 0; jt < 4; ++jt)
            acc[mt][jt] = (f32x4){0.f, 0.f, 0.f, 0.f};

    const int rowA0  = mrow0 + ln;
    const int rowA1  = mrow0 + 16 + ln;
    const int baseA0 = rowA0 * 256;
    const int baseA1 = rowA1 * 256;
    const int r70    = rowA0 & 7;
    const int r71    = rowA1 & 7;

#pragma unroll 1
    for (int kk = 0; kk < 8; ++kk) {
        const int chunk = kk * 4 + kg;      // 16B chunk index (8 halves)
        const int kbase = chunk << 3;       // k element index
        f16x8 ah0 = *reinterpret_cast<const f16x8*>(Ah + baseA0 + ((chunk ^ r70) << 3));
        f16x8 al0 = *reinterpret_cast<const f16x8*>(Al + baseA0 + ((chunk ^ r70) << 3));
        f16x8 ah1 = *reinterpret_cast<const f16x8*>(Ah + baseA1 + ((chunk ^ r71) << 3));
        f16x8 al1 = *reinterpret_cast<const f16x8*>(Al + baseA1 + ((chunk ^ r71) << 3));
#pragma unroll
        for (int jt = 0; jt < 4; ++jt) {
            const int j = jb + jt * 16 + ln;
            const size_t boff = ((size_t)j << 8) + kbase;
            f16x8 bh = *reinterpret_cast<const f16x8*>(Whh + boff);
            f16x8 bl = *reinterpret_cast<const f16x8*>(Whl + boff);
            acc[0][jt] = __builtin_amdgcn_mfma_f32_16x16x32_f16(ah0, bh, acc[0][jt], 0, 0, 0);
            acc[0][jt] = __builtin_amdgcn_mfma_f32_16x16x32_f16(al0, bh, acc[0][jt], 0, 0, 0);
            acc[0][jt] = __builtin_amdgcn_mfma_f32_16x16x32_f16(ah0, bl, acc[0][jt], 0, 0, 0);
            acc[1][jt] = __builtin_amdgcn_mfma_f32_16x16x32_f16(ah1, bh, acc[1][jt], 0, 0, 0);
            acc[1][jt] = __builtin_amdgcn_mfma_f32_16x16x32_f16(al1, bh, acc[1][jt], 0, 0, 0);
            acc[1][jt] = __builtin_amdgcn_mfma_f32_16x16x32_f16(ah1, bl, acc[1][jt], 0, 0, 0);
        }
    }

    // ---- epilogue: per-lane partials over its 4 j per jt, shuffle-reduce
    // over the 16 lanes sharing each node, LDS-combine the 4 j-groups. ----
    float b1v[4], wl0[4], wl1[4], wr0[4], wr1[4];
#pragma unroll
    for (int jt = 0; jt < 4; ++jt) {
        int j = jb + jt * 16 + ln;
        b1v[jt] = b1[j];
        wl0[jt] = W2l[j];        wl1[jt] = W2l[HID + j];
        wr0[jt] = W2r[j];        wr1[jt] = W2r[HID + j];
    }

    float redv[2][4][5];
#pragma unroll
    for (int mt = 0; mt < 2; ++mt) {
#pragma unroll
        for (int rg = 0; rg < 4; ++rg) {
            float s = 0.f, G0 = 0.f, G1 = 0.f, R0 = 0.f, R1 = 0.f;
#pragma unroll
            for (int jt = 0; jt < 4; ++jt) {
                float oo = acc[mt][jt][rg] + b1v[jt];
                s = fmaf(oo, oo, s);
                float pp = fmaxf(oo, 0.f);   // relu(o/D) = relu(o)/D
                G0 = fmaf(pp, wl0[jt], G0);
                G1 = fmaf(pp, wl1[jt], G1);
                R0 = fmaf(pp, wr0[jt], R0);
                R1 = fmaf(pp, wr1[jt], R1);
            }
#pragma unroll
            for (int m = 1; m < 16; m <<= 1) {
                s  += __shfl_xor(s, m);
                G0 += __shfl_xor(G0, m);
                G1 += __shfl_xor(G1, m);
                R0 += __shfl_xor(R0, m);
                R1 += __shfl_xor(R1, m);
            }
            redv[mt][rg][0] = s;  redv[mt][rg][1] = G0; redv[mt][rg][2] = G1;
            redv[mt][rg][3] = R0; redv[mt][rg][4] = R1;
        }
    }

    __syncthreads();                    // A-tile dead; reuse as overlay
    float* red = (float*)Ah;            // [4 jg][64 node][5] = 5 KB
    if (ln == 0) {
#pragma unroll
        for (int mt = 0; mt < 2; ++mt)
#pragma unroll
            for (int rg = 0; rg < 4; ++rg) {
                int n_loc = mrow0 + mt * 16 + kg * 4 + rg;
                int base  = ((w >> 1) * 64 + n_loc) * 5;
                red[base + 0] = redv[mt][rg][0];
                red[base + 1] = redv[mt][rg][1];
                red[base + 2] = redv[mt][rg][2];
                red[base + 3] = redv[mt][rg][3];
                red[base + 4] = redv[mt][rg][4];
            }
    }
    __syncthreads();

    if (t < 64) {
        int n = nb + t;
        if (n < NN) {
            float s = 0.f, G0 = 0.f, G1 = 0.f, R0 = 0.f, R1 = 0.f;
#pragma unroll
            for (int jg = 0; jg < 4; ++jg) {
                const float* pp = red + (jg * 64 + t) * 5;
                s += pp[0]; G0 += pp[1]; G1 += pp[2]; R0 += pp[3]; R1 += pp[4];
            }
            float inv = 1.0f / fmaxf(sqrtf(s), FEPS);
            g[2 * (size_t)n]     = G0 * inv;
            g[2 * (size_t)n + 1] = G1 * inv;
            r[2 * (size_t)n]     = R0 * inv;
            r[2 * (size_t)n + 1] = R1 * inv;
        }
    }
}

// ---------------------------------------------------------------------------
// Shared phase-B + epilogue body (FALLBACK paths only; weights reconstructed
// from fp16 hi+lo, error ~2^-22 rel). Slow strided weight access — paths B/C
// only run if ws_size shrinks below needA (never observed).
// ---------------------------------------------------------------------------
__device__ __forceinline__ void phaseB_epilogue(
    float* smem_f, int t, int l, int nb,
    const __half* __restrict__ Whh, const __half* __restrict__ Whl,
    const float* __restrict__ b1,
    const float* __restrict__ W2l, const float* __restrict__ W2r,
    float* __restrict__ g, float* __restrict__ r)
{
    const int w  = __builtin_amdgcn_readfirstlane(t >> 6);  // 0..15
    const int jb = w * 16;

    float o[16];
#pragma unroll
    for (int i = 0; i < 16; ++i) o[i] = 0.0f;

#pragma unroll 1
    for (int k2 = 0; k2 < 2 * FIN; k2 += 4) {
        const int nc = l ^ ((k2 >> 3) & 31);
        float av0 = smem_f[(k2 + 0) * 64 + nc];
        float av1 = smem_f[(k2 + 1) * 64 + nc];
        float av2 = smem_f[(k2 + 2) * 64 + nc];
        float av3 = smem_f[(k2 + 3) * 64 + nc];
#pragma unroll
        for (int i = 0; i < 16; ++i) {
            const __half* ph = Whh + (size_t)(jb + i) * (2 * FIN) + k2;
            const __half* pl = Whl + (size_t)(jb + i) * (2 * FIN) + k2;
            float oi = o[i];
            oi = fmaf(av0, __half2float(ph[0]) + __half2float(pl[0]), oi);
            oi = fmaf(av1, __half2float(ph[1]) + __half2float(pl[1]), oi);
            oi = fmaf(av2, __half2float(ph[2]) + __half2float(pl[2]), oi);
            oi = fmaf(av3, __half2float(ph[3]) + __half2float(pl[3]), oi);
            o[i] = oi;
        }
    }

    float sq = 0.f, g0 = 0.f, g1 = 0.f, r0 = 0.f, r1 = 0.f;
    const float* b1w  = b1  + jb;
    const float* w2la = W2l + jb;
    const float* w2lb = W2l + HID + jb;
    const float* w2ra = W2r + jb;
    const float* w2rb = W2r + HID + jb;
#pragma unroll
    for (int i = 0; i < 16; ++i) {
        float oo = o[i] + b1w[i];
        sq = fmaf(oo, oo, sq);
        float p = fmaxf(oo, 0.0f);
        g0 = fmaf(p, w2la[i], g0);
        g1 = fmaf(p, w2lb[i], g1);
        r0 = fmaf(p, w2ra[i], r0);
        r1 = fmaf(p, w2rb[i], r1);
    }

    __syncthreads();                          // tile dead; reuse as overlay
    smem_f[0 * 1024 + t] = sq;
    smem_f[1 * 1024 + t] = g0;
    smem_f[2 * 1024 + t] = g1;
    smem_f[3 * 1024 + t] = r0;
    smem_f[4 * 1024 + t] = r1;
    __syncthreads();

    if (t < 64) {
        int n2 = nb + t;
        float sqs = 0.f, G0 = 0.f, G1 = 0.f, R0 = 0.f, R1 = 0.f;
#pragma unroll
        for (int ww = 0; ww < 16; ++ww) {
            sqs += smem_f[0 * 1024 + ww * 64 + t];
            G0  += smem_f[1 * 1024 + ww * 64 + t];
            G1  += smem_f[2 * 1024 + ww * 64 + t];
            R0  += smem_f[3 * 1024 + ww * 64 + t];
            R1  += smem_f[4 * 1024 + ww * 64 + t];
        }
        float inv = 1.0f / fmaxf(sqrtf(sqs), FEPS);
        if (n2 < NN) {
            g[2 * (size_t)n2]     = G0 * inv;
            g[2 * (size_t)n2 + 1] = G1 * inv;
            r[2 * (size_t)n2]     = R0 * inv;
            r[2 * (size_t)n2 + 1] = R1 * inv;
        }
    }
}

// ---------------------------------------------------------------------------
// Paths B/C: fused layer-1 (B = fp16 gather, C = fp32). Fallback only.
// ---------------------------------------------------------------------------
template <bool HALFX>
__global__ __launch_bounds__(1024, 8) void layer1_kernel(
    const int* __restrict__ off, const int* __restrict__ col,
    const float* __restrict__ x, const __half* __restrict__ xh,
    const __half* __restrict__ Whh, const __half* __restrict__ Whl,
    const float* __restrict__ b1,
    const float* __restrict__ W2l, const float* __restrict__ W2r,
    float* __restrict__ g, float* __restrict__ r)
{
    __shared__ float smem_f[256 * 64];

    const int t  = threadIdx.x;
    const int nb = blockIdx.x * 64;
    const int l  = t & 63;

    {
        const int n_loc = t >> 4;
        const int ft    = t & 15;
        const int fbase = ft * 8;
        const int n     = nb + n_loc;
        const bool valid = (n < NN);

        float a[8];
#pragma unroll
        for (int i = 0; i < 8; ++i) a[i] = 0.0f;

        int s0 = 0, s1 = 0;
        if (valid) { s0 = off[n]; s1 = off[n + 1]; }

        int i = s0;
        if (HALFX) {
            for (; i + 3 < s1; i += 4) {
                int c0 = clampN(col[i]);
                int c1 = clampN(col[i + 1]);
                int c2 = clampN(col[i + 2]);
                int c3 = clampN(col[i + 3]);
                uint4 v0 = *(const uint4*)(xh + (size_t)c0 * FIN + fbase);
                uint4 v1 = *(const uint4*)(xh + (size_t)c1 * FIN + fbase);
                uint4 v2 = *(const uint4*)(xh + (size_t)c2 * FIN + fbase);
                uint4 v3 = *(const uint4*)(xh + (size_t)c3 * FIN + fbase);
#pragma unroll
                for (int u = 0; u < 4; ++u) {
                    float2 f0 = __half22float2(__builtin_bit_cast(__half2, (&v0.x)[u]));
                    float2 f1 = __half22float2(__builtin_bit_cast(__half2, (&v1.x)[u]));
                    float2 f2 = __half22float2(__builtin_bit_cast(__half2, (&v2.x)[u]));
                    float2 f3 = __half22float2(__builtin_bit_cast(__half2, (&v3.x)[u]));
                    a[2 * u]     += (f0.x + f1.x) + (f2.x + f3.x);
                    a[2 * u + 1] += (f0.y + f1.y) + (f2.y + f3.y);
                }
            }
            for (; i < s1; ++i) {
                int c0 = clampN(col[i]);
                uint4 v0 = *(const uint4*)(xh + (size_t)c0 * FIN + fbase);
#pragma unroll
                for (int u = 0; u < 4; ++u) {
                    float2 f0 = __half22float2(__builtin_bit_cast(__half2, (&v0.x)[u]));
                    a[2 * u]     += f0.x;
                    a[2 * u + 1] += f0.y;
                }
            }
        } else {
            for (; i < s1; ++i) {
                int c0 = clampN(col[i]);
                const float4* p0 = (const float4*)(x + (size_t)c0 * FIN + fbase);
                float4 v00 = p0[0], v01 = p0[1];
                a[0] += v00.x; a[1] += v00.y; a[2] += v00.z; a[3] += v00.w;
                a[4] += v01.x; a[5] += v01.y; a[6] += v01.z; a[7] += v01.w;
            }
        }
        float ic = 1.0f / fmaxf((float)(s1 - s0), 1.0f);
#pragma unroll
        for (int k = 0; k < 8; ++k) {
            int f = fbase + k;
            smem_f[f * 64 + (n_loc ^ ((f >> 3) & 31))] = a[k] * ic;
        }
        const float4* sp = (const float4*)(x + (size_t)(valid ? n : 0) * FIN + fbase);
        float4 s0v = valid ? sp[0] : make_float4(0.f, 0.f, 0.f, 0.f);
        float4 s1v = valid ? sp[1] : make_float4(0.f, 0.f, 0.f, 0.f);
        float sv[8] = {s0v.x, s0v.y, s0v.z, s0v.w, s1v.x, s1v.y, s1v.z, s1v.w};
#pragma unroll
        for (int k = 0; k < 8; ++k) {
            int f = FIN + fbase + k;
            smem_f[f * 64 + (n_loc ^ ((f >> 3) & 31))] = sv[k];
        }
    }
    __syncthreads();

    phaseB_epilogue(smem_f, t, l, nb, Whh, Whl, b1, W2l, W2r, g, r);
}

// layer-2 mean via CSR gather of g, +b2, +lin_r, L2-normalize, log_softmax
__global__ __launch_bounds__(256) void finalize_kernel(
    const int* __restrict__ off, const int* __restrict__ col,
    const float* __restrict__ g, const float* __restrict__ r,
    const float* __restrict__ b2,
    float* __restrict__ out)
{
    int n = blockIdx.x * 256 + threadIdx.x;
    if (n >= NN) return;
    int s0 = off[n], s1 = off[n + 1];
    float z0 = 0.0f, z1 = 0.0f, y0b = 0.0f, y1b = 0.0f;
    int i = s0;
    for (; i + 1 < s1; i += 2) {
        int sa = clampN(col[i]);
        int sb = clampN(col[i + 1]);
        float2 va = *(const float2*)(g + 2 * (size_t)sa);
        float2 vb = *(const float2*)(g + 2 * (size_t)sb);
        z0 += va.x; z1 += va.y;
        y0b += vb.x; y1b += vb.y;
    }
    if (i < s1) {
        int sa = clampN(col[i]);
        float2 va = *(const float2*)(g + 2 * (size_t)sa);
        z0 += va.x; z1 += va.y;
    }
    z0 += y0b; z1 += y1b;
    float ic = 1.0f / fmaxf((float)(s1 - s0), 1.0f);
    z0 = z0 * ic + b2[0] + r[2 * (size_t)n];
    z1 = z1 * ic + b2[1] + r[2 * (size_t)n + 1];
    float d = 1.0f / fmaxf(sqrtf(z0 * z0 + z1 * z1), FEPS);
    float y0 = z0 * d, y1 = z1 * d;
    float m = fmaxf(y0, y1);
    float lg = m + logf(__expf(y0 - m) + __expf(y1 - m));
    out[2 * (size_t)n]     = y0 - lg;
    out[2 * (size_t)n + 1] = y1 - lg;
}

// ---------------------------------------------------------------------------
extern "C" void kernel_launch(void* const* d_in, const int* in_sizes, int n_in,
                              void* d_out, int out_size, void* d_ws, size_t ws_size,
                              hipStream_t stream) {
    // setup_inputs order: x, edge_index, W1_l, b1, W1_r, W2_l, b2, W2_r
    const float* x   = (const float*)d_in[0];
    const int*   ei  = (const int*)d_in[1];
    const float* W1l = (const float*)d_in[2];
    const float* b1  = (const float*)d_in[3];
    const float* W1r = (const float*)d_in[4];
    const float* W2l = (const float*)d_in[5];
    const float* b2  = (const float*)d_in[6];
    const float* W2r = (const float*)d_in[7];

    const int nsb = (NN + 1023) / 1024;          // 98 scan blocks
    const int ncv = (NN * FIN / 8 + 255) / 256;  // convert blocks
    const int ecb = (NE + 255) / 256;            // edge blocks

    const size_t tailWords = (size_t)2 * NN + (NN + 1) + NE + 4 * NN + 128;
    const size_t needB = (size_t)256 * 256 * 4 + (size_t)NN * FIN * 2 +
                         tailWords * 4;
    const size_t needA = needB + (size_t)NN * FIN * 4;   // + fp32 agg

    // host-side constants: graph-safe
    bool pathA = (ws_size >= needA);
    bool pathB = !pathA && (ws_size >= needB);
    bool half  = pathA || pathB;

    char* p = (char*)d_ws;
    __half* Whh = (__half*)p;             p += (size_t)256 * 256 * 2;
    __half* Whl = (__half*)p;             p += (size_t)256 * 256 * 2;
    __half* xh = nullptr;
    if (half) { xh = (__half*)p;          p += (size_t)NN * FIN * 2; }
    float* agg = nullptr;
    if (pathA) { agg = (float*)p;         p += (size_t)NN * FIN * 4; }

    int*   cnt  = (int*)p;
    int*   cur  = cnt + NN;
    int*   off  = cur + NN;                      // NN+1
    int*   col  = off + NN + 1;                  // NE
    float* g    = (float*)(col + NE);            // NN*2
    float* r    = g + 2 * (size_t)NN;            // NN*2
    int*   bsum = (int*)(r + 2 * (size_t)NN);    // 128

    hipMemsetAsync(cnt, 0, 2 * (size_t)NN * sizeof(int), stream);

    int cv = half ? ncv : 0;
    setup_kernel<<<256 + cv + ecb, 256, 0, stream>>>(ei, x, W1l, W1r,
                                                     Whh, Whl, xh, cnt, cv);
    scan_a_kernel<<<nsb, 1024, 0, stream>>>(cnt, off, bsum);
    scan_b_kernel<<<1, 128, 0, stream>>>(bsum, off, nsb);
    scan_c_kernel<<<nsb, 1024, 0, stream>>>(bsum, off);
    fill_kernel<<<ecb, 256, 0, stream>>>(ei, off, cur, col);

    if (pathA) {
        gather_kernel<<<(NN * 16 + 255) / 256, 256, 0, stream>>>(off, col, xh,
                                                                 agg);
        gemm_mfma_kernel<<<(NN + 63) / 64, 512, 0, stream>>>(agg, x, Whh, Whl,
                                                             b1, W2l, W2r, g, r);
    } else if (pathB) {
        layer1_kernel<true><<<(NN + 63) / 64, 1024, 0, stream>>>(
            off, col, x, xh, Whh, Whl, b1, W2l, W2r, g, r);
    } else {
        layer1_kernel<false><<<(NN + 63) / 64, 1024, 0, stream>>>(
            off, col, x, xh, Whh, Whl, b1, W2l, W2r, g, r);
    }
    finalize_kernel<<<(NN + 255) / 256, 256, 0, stream>>>(off, col, g, r, b2,
                                                          (float*)d_out);
}

// Round 2
// 268.307 us; speedup vs baseline: 1.2332x; 1.2332x over previous
//
#include <hip/hip_runtime.h>
#include <hip/hip_fp16.h>

// Problem constants (from reference)
#define NN  100000   // nodes
#define FIN 128      // in features
#define HID 256      // hidden
#define NE  600000   // edges
#define FEPS 1e-12f

// ---------------------------------------------------------------------------
// Workspace layout (unchanged sizes):
//  Path A (~82.3 MB): Bfh|Bfl[65536]h frag-order (=256KB) | xh[NN*FIN]h |
//                     agg[NN*FIN]f | cnt|cur|off|col | g|r | bsum
// Evidence log:
//  - R5: bf16 FEATURES fail precision; fp16 OK (absmax 0.0156 vs thr 0.0327).
//  - R6..R12: occupancy/bytes/atomics levers exhausted (291 us fused).
//  - R13: SPLIT WINS: barrier-free gather <50 us; gemm exposed: 265 us.
//  - R14/R15: VALU GEMM tuned to 245 us; fp32-FMA floor 83 us is the wall.
//  - R16: MFMA 3-product fp16 emulation (AhBh+AlBh+AhBl): 245->147.8 us,
//    absmax unchanged 0.0156. BUT MfmaUtil 10.7% (MFMA busy ~16us of 148),
//    VALUBusy 13%, HBM 4.7% => latency-bound on B loads: [j][k] layout makes
//    each wave B-load a 16-line 512B-stride scatter; unroll 1 serializes
//    load-wait-MFMA per kk step.
//  - R17 (this): B in fragment-contiguous layout [kchunk][jgroup][lane][8]
//    => per-(kk,jt) load is one dense 1KB coalesced burst. Full kk unroll
//    => compiler hoists loads ahead of MFMAs (VGPR 64->~128 cap ok).
//    Predicted: gemm 147.8 -> ~55-75 us, MfmaUtil -> 25-35%, total ~240 us.
// ---------------------------------------------------------------------------

typedef _Float16 f16x8 __attribute__((ext_vector_type(8)));
typedef float    f32x4 __attribute__((ext_vector_type(4)));

__device__ __forceinline__ int clampN(int v) {
    return ((unsigned)v < (unsigned)NN) ? v : 0;
}
// int64 vs int32 edge_index: little-endian int64 (<2^31) => odd words all 0.
__device__ __forceinline__ int detect4(const int* ei) {
    return ((ei[1] | ei[3] | ei[5] | ei[7]) == 0) ? 1 : 0;
}
__device__ __forceinline__ int ld_src(const int* ei, int e, int f) {
    return f ? ei[2 * e] : ei[e];
}
__device__ __forceinline__ int ld_dst(const int* ei, int e, int f) {
    return f ? ei[2 * (NE + e)] : ei[NE + e];
}

// Fragment-order index for weight element (j, k):
// [kchunk = k>>5][jgroup = j>>4][lane = ((k>>3)&3)*16 + (j&15)][e = k&7]
__device__ __forceinline__ size_t fragIdx(int j, int k) {
    return ((size_t)((k >> 5) * 16 + (j >> 4)) * 64 +
            (size_t)(((k >> 3) & 3) * 16 + (j & 15))) * 8 + (k & 7);
}

// ---------------------------------------------------------------------------
// Setup (fused): blocks [0,256) split weights to fp16 hi/lo in FRAG layout;
// [256,256+ncv) x->fp16; [256+ncv, ...) in-degree count (cnt pre-zeroed).
// ---------------------------------------------------------------------------
__global__ __launch_bounds__(256) void setup_kernel(
    const int* __restrict__ ei,
    const float* __restrict__ x,
    const float* __restrict__ W1l, const float* __restrict__ W1r,
    __half* __restrict__ Bfh, __half* __restrict__ Bfl,
    __half* __restrict__ xh,
    int* __restrict__ cnt, int ncv)
{
    int b = blockIdx.x;
    int t = threadIdx.x;
    if (b < 256) {
        int j = b, k2 = t;   // row j of [W1l | W1r], contiguous k
        float v = (k2 < FIN) ? W1l[(size_t)j * FIN + k2]
                             : W1r[(size_t)j * FIN + (k2 - FIN)];
        __half h  = __float2half_rn(v);
        __half lo = __float2half_rn(v - __half2float(h));
        size_t fi = fragIdx(j, k2);
        Bfh[fi] = h;
        Bfl[fi] = lo;
    } else if (b < 256 + ncv) {
        int idx = (b - 256) * 256 + t;           // 8-float group
        if (idx < NN * FIN / 8) {
            const float4* px = (const float4*)(x + (size_t)idx * 8);
            float4 v0 = px[0], v1 = px[1];
            __half2 h0 = __float22half2_rn(make_float2(v0.x, v0.y));
            __half2 h1 = __float22half2_rn(make_float2(v0.z, v0.w));
            __half2 h2 = __float22half2_rn(make_float2(v1.x, v1.y));
            __half2 h3 = __float22half2_rn(make_float2(v1.z, v1.w));
            uint4 u;
            u.x = __builtin_bit_cast(unsigned, h0);
            u.y = __builtin_bit_cast(unsigned, h1);
            u.z = __builtin_bit_cast(unsigned, h2);
            u.w = __builtin_bit_cast(unsigned, h3);
            ((uint4*)xh)[idx] = u;
        }
    } else {
        int e = (b - 256 - ncv) * 256 + t;
        if (e < NE) {
            int f = detect4(ei);
            atomicAdd(cnt + clampN(ld_dst(ei, e, f)), 1);
        }
    }
}

// 3-phase parallel exclusive scan of cnt[NN] -> off[NN+1]
__global__ __launch_bounds__(1024) void scan_a_kernel(
    const int* __restrict__ cnt, int* __restrict__ off, int* __restrict__ bsum)
{
    __shared__ int sm[1024];
    int t = threadIdx.x;
    int idx = blockIdx.x * 1024 + t;
    int v = (idx < NN) ? cnt[idx] : 0;
    sm[t] = v;
    __syncthreads();
    for (int d = 1; d < 1024; d <<= 1) {
        int w = (t >= d) ? sm[t - d] : 0;
        __syncthreads();
        sm[t] += w;
        __syncthreads();
    }
    if (idx < NN) off[idx] = sm[t] - v;
    if (t == 1023) bsum[blockIdx.x] = sm[1023];
}
__global__ __launch_bounds__(128) void scan_b_kernel(
    int* __restrict__ bsum, int* __restrict__ off, int nblocks)
{
    __shared__ int sm[128];
    int t = threadIdx.x;
    int v = (t < nblocks) ? bsum[t] : 0;
    sm[t] = v;
    __syncthreads();
    for (int d = 1; d < 128; d <<= 1) {
        int w = (t >= d) ? sm[t - d] : 0;
        __syncthreads();
        sm[t] += w;
        __syncthreads();
    }
    if (t < nblocks) bsum[t] = sm[t] - v;
    if (t == 0) off[NN] = NE;
}
__global__ __launch_bounds__(1024) void scan_c_kernel(
    const int* __restrict__ bsum, int* __restrict__ off)
{
    int idx = blockIdx.x * 1024 + threadIdx.x;
    if (idx < NN) off[idx] += bsum[blockIdx.x];
}

// place src ids into CSR slots
__global__ __launch_bounds__(256) void fill_kernel(
    const int* __restrict__ ei,
    const int* __restrict__ off, int* __restrict__ cur, int* __restrict__ col)
{
    int e = blockIdx.x * 256 + threadIdx.x;
    if (e >= NE) return;
    int f = detect4(ei);
    int src = clampN(ld_src(ei, e, f));
    int dst = clampN(ld_dst(ei, e, f));
    int p = atomicAdd(cur + dst, 1);
    col[off[dst] + p] = src;
}

// ---------------------------------------------------------------------------
// Path A, stage 1: barrier-free gather. 1 thread per (node, 16B fp16 chunk);
// 4-wide independent-load loop; mean written to global agg (fp32).
// ---------------------------------------------------------------------------
__global__ __launch_bounds__(256) void gather_kernel(
    const int* __restrict__ off, const int* __restrict__ col,
    const __half* __restrict__ xh, float* __restrict__ agg)
{
    int idx = blockIdx.x * 256 + threadIdx.x;
    if (idx >= NN * 16) return;
    int n     = idx >> 4;
    int ft    = idx & 15;
    int fbase = ft * 8;

    float a[8];
#pragma unroll
    for (int i = 0; i < 8; ++i) a[i] = 0.0f;

    int s0 = off[n], s1 = off[n + 1];
    int i = s0;
    for (; i + 3 < s1; i += 4) {            // 4 independent 16B loads
        int c0 = clampN(col[i]);
        int c1 = clampN(col[i + 1]);
        int c2 = clampN(col[i + 2]);
        int c3 = clampN(col[i + 3]);
        uint4 v0 = *(const uint4*)(xh + (size_t)c0 * FIN + fbase);
        uint4 v1 = *(const uint4*)(xh + (size_t)c1 * FIN + fbase);
        uint4 v2 = *(const uint4*)(xh + (size_t)c2 * FIN + fbase);
        uint4 v3 = *(const uint4*)(xh + (size_t)c3 * FIN + fbase);
#pragma unroll
        for (int u = 0; u < 4; ++u) {
            float2 f0 = __half22float2(__builtin_bit_cast(__half2, (&v0.x)[u]));
            float2 f1 = __half22float2(__builtin_bit_cast(__half2, (&v1.x)[u]));
            float2 f2 = __half22float2(__builtin_bit_cast(__half2, (&v2.x)[u]));
            float2 f3 = __half22float2(__builtin_bit_cast(__half2, (&v3.x)[u]));
            a[2 * u]     += (f0.x + f1.x) + (f2.x + f3.x);
            a[2 * u + 1] += (f0.y + f1.y) + (f2.y + f3.y);
        }
    }
    for (; i < s1; ++i) {
        int c0 = clampN(col[i]);
        uint4 v0 = *(const uint4*)(xh + (size_t)c0 * FIN + fbase);
#pragma unroll
        for (int u = 0; u < 4; ++u) {
            float2 f0 = __half22float2(__builtin_bit_cast(__half2, (&v0.x)[u]));
            a[2 * u]     += f0.x;
            a[2 * u + 1] += f0.y;
        }
    }
    float ic = 1.0f / fmaxf((float)(s1 - s0), 1.0f);
    float4* dst = (float4*)(agg + (size_t)n * FIN + fbase);
    dst[0] = make_float4(a[0] * ic, a[1] * ic, a[2] * ic, a[3] * ic);
    dst[1] = make_float4(a[4] * ic, a[5] * ic, a[6] * ic, a[7] * ic);
}

// ---------------------------------------------------------------------------
// fp32 -> fp16 hi/lo split, written to XOR-swizzled LDS tiles.
// Swizzle: 16B chunk c of row r lives at chunk (c ^ (r&7)).
// ---------------------------------------------------------------------------
__device__ __forceinline__ void storeHiLo4(
    __half* Ah, __half* Al, int row, int k, float4 v)
{
    int addr = row * 256 + ((((k >> 3) ^ (row & 7)) << 3) | (k & 7));
    __half h0 = __float2half_rn(v.x), h1 = __float2half_rn(v.y);
    __half h2 = __float2half_rn(v.z), h3 = __float2half_rn(v.w);
    __half l0 = __float2half_rn(v.x - __half2float(h0));
    __half l1 = __float2half_rn(v.y - __half2float(h1));
    __half l2 = __float2half_rn(v.z - __half2float(h2));
    __half l3 = __float2half_rn(v.w - __half2float(h3));
    uint2 uh, ul;
    uh.x = __builtin_bit_cast(unsigned, __halves2half2(h0, h1));
    uh.y = __builtin_bit_cast(unsigned, __halves2half2(h2, h3));
    ul.x = __builtin_bit_cast(unsigned, __halves2half2(l0, l1));
    ul.y = __builtin_bit_cast(unsigned, __halves2half2(l2, l3));
    *(uint2*)(Ah + addr) = uh;
    *(uint2*)(Al + addr) = ul;
}

// ---------------------------------------------------------------------------
// Path A, stage 2: MFMA GEMM with exact fp32 emulation.
// Block: 512 thr (8 waves) = 64 nodes x 256 j, K=256.
// Wave (w): node-half (w&1)*32 (2 M-tiles), j-group (w>>1)*64 (4 N-tiles).
// Per K-step (32): 3 MFMAs/tile: Ah*Bh + Al*Bh + Ah*Bl  (fp32 acc).
// A hi/lo from LDS (ds_read_b128, swizzled); B hi/lo fp16 from global in
// FRAGMENT-CONTIGUOUS order: each (kk,jt) load = dense 1KB wave burst.
// kk loop fully unrolled so the compiler prefetches loads across steps.
// C layout (m89-verified): col=lane&15 (j), row=(lane>>4)*4+reg (node).
// ---------------------------------------------------------------------------
__global__ __launch_bounds__(512, 4) void gemm_mfma_kernel(
    const float* __restrict__ agg, const float* __restrict__ x,
    const __half* __restrict__ Bfh, const __half* __restrict__ Bfl,
    const float* __restrict__ b1,
    const float* __restrict__ W2l, const float* __restrict__ W2r,
    float* __restrict__ g, float* __restrict__ r)
{
    __shared__ __half Ah[64 * 256];   // 32 KB
    __shared__ __half Al[64 * 256];   // 32 KB

    const int t  = threadIdx.x;
    const int nb = blockIdx.x * 64;

    // ---- stage A: coalesced float4 streams -> hi/lo fp16 swizzled LDS ----
    {
        const float4* aggF = (const float4*)agg;
        const float4* xF   = (const float4*)x;
        const float4 z4 = make_float4(0.f, 0.f, 0.f, 0.f);
#pragma unroll
        for (int i = 0; i < 4; ++i) {
            int idx   = i * 512 + t;        // 0..2047 = 64 rows x 32 f4
            int n_loc = idx >> 5;
            int kq    = idx & 31;
            int n     = nb + n_loc;
            bool valid = (n < NN);
            size_t base = (size_t)(valid ? n : 0) * 32 + kq;
            float4 va = aggF[base];
            float4 vx = xF[base];
            if (!valid) { va = z4; vx = z4; }
            storeHiLo4(Ah, Al, n_loc, kq * 4, va);          // k in [0,128)
            storeHiLo4(Ah, Al, n_loc, FIN + kq * 4, vx);    // k in [128,256)
        }
    }
    __syncthreads();

    const int l     = t & 63;
    const int w     = t >> 6;          // wave 0..7
    const int ln    = l & 15;
    const int kg    = l >> 4;          // 0..3 (K sub-chunk of the frag)
    const int mrow0 = (w & 1) * 32;    // node offset within tile
    const int jb    = (w >> 1) * 64;   // j offset

    f32x4 acc[2][4];
#pragma unroll
    for (int mt = 0; mt < 2; ++mt)
#pragma unroll
        for (int jt = 0; jt < 4; ++jt)
            acc[mt][jt] = (f32x4){0.f, 0.f, 0.f, 0.f};

    const int rowA0  = mrow0 + ln;
    const int rowA1  = mrow0 + 16 + ln;
    const int baseA0 = rowA0 * 256;
    const int baseA1 = rowA1 * 256;
    const int r70    = rowA0 & 7;
    const int r71    = rowA1 & 7;

    // frag-layout wave base: jgroup0 = (w>>1)*4, + lane term
    const size_t bbase = (size_t)(w >> 1) * 2048 + (size_t)l * 8;
    const __half* __restrict__ bhp = Bfh + bbase;
    const __half* __restrict__ blp = Bfl + bbase;

#pragma unroll
    for (int kk = 0; kk < 8; ++kk) {
        const int chunk = kk * 4 + kg;      // 16B chunk index (8 halves)
        f16x8 ah0 = *reinterpret_cast<const f16x8*>(Ah + baseA0 + ((chunk ^ r70) << 3));
        f16x8 al0 = *reinterpret_cast<const f16x8*>(Al + baseA0 + ((chunk ^ r70) << 3));
        f16x8 ah1 = *reinterpret_cast<const f16x8*>(Ah + baseA1 + ((chunk ^ r71) << 3));
        f16x8 al1 = *reinterpret_cast<const f16x8*>(Al + baseA1 + ((chunk ^ r71) << 3));
#pragma unroll
        for (int jt = 0; jt < 4; ++jt) {
            f16x8 bh = *reinterpret_cast<const f16x8*>(bhp + kk * 8192 + jt * 512);
            f16x8 bl = *reinterpret_cast<const f16x8*>(blp + kk * 8192 + jt * 512);
            acc[0][jt] = __builtin_amdgcn_mfma_f32_16x16x32_f16(ah0, bh, acc[0][jt], 0, 0, 0);
            acc[1][jt] = __builtin_amdgcn_mfma_f32_16x16x32_f16(ah1, bh, acc[1][jt], 0, 0, 0);
            acc[0][jt] = __builtin_amdgcn_mfma_f32_16x16x32_f16(al0, bh, acc[0][jt], 0, 0, 0);
            acc[1][jt] = __builtin_amdgcn_mfma_f32_16x16x32_f16(al1, bh, acc[1][jt], 0, 0, 0);
            acc[0][jt] = __builtin_amdgcn_mfma_f32_16x16x32_f16(ah0, bl, acc[0][jt], 0, 0, 0);
            acc[1][jt] = __builtin_amdgcn_mfma_f32_16x16x32_f16(ah1, bl, acc[1][jt], 0, 0, 0);
        }
    }

    // ---- epilogue: per-lane partials over its 4 j per jt, shuffle-reduce
    // over the 16 lanes sharing each node, LDS-combine the 4 j-groups. ----
    float b1v[4], wl0[4], wl1[4], wr0[4], wr1[4];
#pragma unroll
    for (int jt = 0; jt < 4; ++jt) {
        int j = jb + jt * 16 + ln;
        b1v[jt] = b1[j];
        wl0[jt] = W2l[j];        wl1[jt] = W2l[HID + j];
        wr0[jt] = W2r[j];        wr1[jt] = W2r[HID + j];
    }

    float redv[2][4][5];
#pragma unroll
    for (int mt = 0; mt < 2; ++mt) {
#pragma unroll
        for (int rg = 0; rg < 4; ++rg) {
            float s = 0.f, G0 = 0.f, G1 = 0.f, R0 = 0.f, R1 = 0.f;
#pragma unroll
            for (int jt = 0; jt < 4; ++jt) {
                float oo = acc[mt][jt][rg] + b1v[jt];
                s = fmaf(oo, oo, s);
                float pp = fmaxf(oo, 0.f);   // relu(o/D) = relu(o)/D
                G0 = fmaf(pp, wl0[jt], G0);
                G1 = fmaf(pp, wl1[jt], G1);
                R0 = fmaf(pp, wr0[jt], R0);
                R1 = fmaf(pp, wr1[jt], R1);
            }
#pragma unroll
            for (int m = 1; m < 16; m <<= 1) {
                s  += __shfl_xor(s, m);
                G0 += __shfl_xor(G0, m);
                G1 += __shfl_xor(G1, m);
                R0 += __shfl_xor(R0, m);
                R1 += __shfl_xor(R1, m);
            }
            redv[mt][rg][0] = s;  redv[mt][rg][1] = G0; redv[mt][rg][2] = G1;
            redv[mt][rg][3] = R0; redv[mt][rg][4] = R1;
        }
    }

    __syncthreads();                    // A-tile dead; reuse as overlay
    float* red = (float*)Ah;            // [4 jg][64 node][5] = 5 KB
    if (ln == 0) {
#pragma unroll
        for (int mt = 0; mt < 2; ++mt)
#pragma unroll
            for (int rg = 0; rg < 4; ++rg) {
                int n_loc = mrow0 + mt * 16 + kg * 4 + rg;
                int base  = ((w >> 1) * 64 + n_loc) * 5;
                red[base + 0] = redv[mt][rg][0];
                red[base + 1] = redv[mt][rg][1];
                red[base + 2] = redv[mt][rg][2];
                red[base + 3] = redv[mt][rg][3];
                red[base + 4] = redv[mt][rg][4];
            }
    }
    __syncthreads();

    if (t < 64) {
        int n = nb + t;
        if (n < NN) {
            float s = 0.f, G0 = 0.f, G1 = 0.f, R0 = 0.f, R1 = 0.f;
#pragma unroll
            for (int jg = 0; jg < 4; ++jg) {
                const float* pp = red + (jg * 64 + t) * 5;
                s += pp[0]; G0 += pp[1]; G1 += pp[2]; R0 += pp[3]; R1 += pp[4];
            }
            float inv = 1.0f / fmaxf(sqrtf(s), FEPS);
            g[2 * (size_t)n]     = G0 * inv;
            g[2 * (size_t)n + 1] = G1 * inv;
            r[2 * (size_t)n]     = R0 * inv;
            r[2 * (size_t)n + 1] = R1 * inv;
        }
    }
}

// ---------------------------------------------------------------------------
// Shared phase-B + epilogue body (FALLBACK paths only; weights reconstructed
// from fp16 hi+lo in frag layout, error ~2^-22 rel). Never runs on this
// harness (ws_size >= needA proven).
// ---------------------------------------------------------------------------
__device__ __forceinline__ void phaseB_epilogue(
    float* smem_f, int t, int l, int nb,
    const __half* __restrict__ Bfh, const __half* __restrict__ Bfl,
    const float* __restrict__ b1,
    const float* __restrict__ W2l, const float* __restrict__ W2r,
    float* __restrict__ g, float* __restrict__ r)
{
    const int w  = __builtin_amdgcn_readfirstlane(t >> 6);  // 0..15
    const int jb = w * 16;

    float o[16];
#pragma unroll
    for (int i = 0; i < 16; ++i) o[i] = 0.0f;

#pragma unroll 1
    for (int k2 = 0; k2 < 2 * FIN; k2 += 4) {
        const int nc = l ^ ((k2 >> 3) & 31);
        float av0 = smem_f[(k2 + 0) * 64 + nc];
        float av1 = smem_f[(k2 + 1) * 64 + nc];
        float av2 = smem_f[(k2 + 2) * 64 + nc];
        float av3 = smem_f[(k2 + 3) * 64 + nc];
#pragma unroll
        for (int i = 0; i < 16; ++i) {
            // frag-layout address of (j=jb+i, k2): e = k2&7 in {0,4}; 4 elems
            // contiguous within one 8-elem chunk of one lane.
            const size_t fb = ((size_t)((k2 >> 5) * 16 + ((jb + i) >> 4)) * 64 +
                               (size_t)(((k2 >> 3) & 3) * 16 + ((jb + i) & 15))) * 8 +
                              (k2 & 7);
            const __half* ph = Bfh + fb;
            const __half* pl = Bfl + fb;
            float oi = o[i];
            oi = fmaf(av0, __half2float(ph[0]) + __half2float(pl[0]), oi);
            oi = fmaf(av1, __half2float(ph[1]) + __half2float(pl[1]), oi);
            oi = fmaf(av2, __half2float(ph[2]) + __half2float(pl[2]), oi);
            oi = fmaf(av3, __half2float(ph[3]) + __half2float(pl[3]), oi);
            o[i] = oi;
        }
    }

    float sq = 0.f, g0 = 0.f, g1 = 0.f, r0 = 0.f, r1 = 0.f;
    const float* b1w  = b1  + jb;
    const float* w2la = W2l + jb;
    const float* w2lb = W2l + HID + jb;
    const float* w2ra = W2r + jb;
    const float* w2rb = W2r + HID + jb;
#pragma unroll
    for (int i = 0; i < 16; ++i) {
        float oo = o[i] + b1w[i];
        sq = fmaf(oo, oo, sq);
        float p = fmaxf(oo, 0.0f);
        g0 = fmaf(p, w2la[i], g0);
        g1 = fmaf(p, w2lb[i], g1);
        r0 = fmaf(p, w2ra[i], r0);
        r1 = fmaf(p, w2rb[i], r1);
    }

    __syncthreads();                          // tile dead; reuse as overlay
    smem_f[0 * 1024 + t] = sq;
    smem_f[1 * 1024 + t] = g0;
    smem_f[2 * 1024 + t] = g1;
    smem_f[3 * 1024 + t] = r0;
    smem_f[4 * 1024 + t] = r1;
    __syncthreads();

    if (t < 64) {
        int n2 = nb + t;
        float sqs = 0.f, G0 = 0.f, G1 = 0.f, R0 = 0.f, R1 = 0.f;
#pragma unroll
        for (int ww = 0; ww < 16; ++ww) {
            sqs += smem_f[0 * 1024 + ww * 64 + t];
            G0  += smem_f[1 * 1024 + ww * 64 + t];
            G1  += smem_f[2 * 1024 + ww * 64 + t];
            R0  += smem_f[3 * 1024 + ww * 64 + t];
            R1  += smem_f[4 * 1024 + ww * 64 + t];
        }
        float inv = 1.0f / fmaxf(sqrtf(sqs), FEPS);
        if (n2 < NN) {
            g[2 * (size_t)n2]     = G0 * inv;
            g[2 * (size_t)n2 + 1] = G1 * inv;
            r[2 * (size_t)n2]     = R0 * inv;
            r[2 * (size_t)n2 + 1] = R1 * inv;
        }
    }
}

// ---------------------------------------------------------------------------
// Paths B/C: fused layer-1 (B = fp16 gather, C = fp32). Fallback only.
// ---------------------------------------------------------------------------
template <bool HALFX>
__global__ __launch_bounds__(1024, 8) void layer1_kernel(
    const int* __restrict__ off, const int* __restrict__ col,
    const float* __restrict__ x, const __half* __restrict__ xh,
    const __half* __restrict__ Bfh, const __half* __restrict__ Bfl,
    const float* __restrict__ b1,
    const float* __restrict__ W2l, const float* __restrict__ W2r,
    float* __restrict__ g, float* __restrict__ r)
{
    __shared__ float smem_f[256 * 64];

    const int t  = threadIdx.x;
    const int nb = blockIdx.x * 64;
    const int l  = t & 63;

    {
        const int n_loc = t >> 4;
        const int ft    = t & 15;
        const int fbase = ft * 8;
        const int n     = nb + n_loc;
        const bool valid = (n < NN);

        float a[8];
#pragma unroll
        for (int i = 0; i < 8; ++i) a[i] = 0.0f;

        int s0 = 0, s1 = 0;
        if (valid) { s0 = off[n]; s1 = off[n + 1]; }

        int i = s0;
        if (HALFX) {
            for (; i + 3 < s1; i += 4) {
                int c0 = clampN(col[i]);
                int c1 = clampN(col[i + 1]);
                int c2 = clampN(col[i + 2]);
                int c3 = clampN(col[i + 3]);
                uint4 v0 = *(const uint4*)(xh + (size_t)c0 * FIN + fbase);
                uint4 v1 = *(const uint4*)(xh + (size_t)c1 * FIN + fbase);
                uint4 v2 = *(const uint4*)(xh + (size_t)c2 * FIN + fbase);
                uint4 v3 = *(const uint4*)(xh + (size_t)c3 * FIN + fbase);
#pragma unroll
                for (int u = 0; u < 4; ++u) {
                    float2 f0 = __half22float2(__builtin_bit_cast(__half2, (&v0.x)[u]));
                    float2 f1 = __half22float2(__builtin_bit_cast(__half2, (&v1.x)[u]));
                    float2 f2 = __half22float2(__builtin_bit_cast(__half2, (&v2.x)[u]));
                    float2 f3 = __half22float2(__builtin_bit_cast(__half2, (&v3.x)[u]));
                    a[2 * u]     += (f0.x + f1.x) + (f2.x + f3.x);
                    a[2 * u + 1] += (f0.y + f1.y) + (f2.y + f3.y);
                }
            }
            for (; i < s1; ++i) {
                int c0 = clampN(col[i]);
                uint4 v0 = *(const uint4*)(xh + (size_t)c0 * FIN + fbase);
#pragma unroll
                for (int u = 0; u < 4; ++u) {
                    float2 f0 = __half22float2(__builtin_bit_cast(__half2, (&v0.x)[u]));
                    a[2 * u]     += f0.x;
                    a[2 * u + 1] += f0.y;
                }
            }
        } else {
            for (; i < s1; ++i) {
                int c0 = clampN(col[i]);
                const float4* p0 = (const float4*)(x + (size_t)c0 * FIN + fbase);
                float4 v00 = p0[0], v01 = p0[1];
                a[0] += v00.x; a[1] += v00.y; a[2] += v00.z; a[3] += v00.w;
                a[4] += v01.x; a[5] += v01.y; a[6] += v01.z; a[7] += v01.w;
            }
        }
        float ic = 1.0f / fmaxf((float)(s1 - s0), 1.0f);
#pragma unroll
        for (int k = 0; k < 8; ++k) {
            int f = fbase + k;
            smem_f[f * 64 + (n_loc ^ ((f >> 3) & 31))] = a[k] * ic;
        }
        const float4* sp = (const float4*)(x + (size_t)(valid ? n : 0) * FIN + fbase);
        float4 s0v = valid ? sp[0] : make_float4(0.f, 0.f, 0.f, 0.f);
        float4 s1v = valid ? sp[1] : make_float4(0.f, 0.f, 0.f, 0.f);
        float sv[8] = {s0v.x, s0v.y, s0v.z, s0v.w, s1v.x, s1v.y, s1v.z, s1v.w};
#pragma unroll
        for (int k = 0; k < 8; ++k) {
            int f = FIN + fbase + k;
            smem_f[f * 64 + (n_loc ^ ((f >> 3) & 31))] = sv[k];
        }
    }
    __syncthreads();

    phaseB_epilogue(smem_f, t, l, nb, Bfh, Bfl, b1, W2l, W2r, g, r);
}

// layer-2 mean via CSR gather of g, +b2, +lin_r, L2-normalize, log_softmax
__global__ __launch_bounds__(256) void finalize_kernel(
    const int* __restrict__ off, const int* __restrict__ col,
    const float* __restrict__ g, const float* __restrict__ r,
    const float* __restrict__ b2,
    float* __restrict__ out)
{
    int n = blockIdx.x * 256 + threadIdx.x;
    if (n >= NN) return;
    int s0 = off[n], s1 = off[n + 1];
    float z0 = 0.0f, z1 = 0.0f, y0b = 0.0f, y1b = 0.0f;
    int i = s0;
    for (; i + 1 < s1; i += 2) {
        int sa = clampN(col[i]);
        int sb = clampN(col[i + 1]);
        float2 va = *(const float2*)(g + 2 * (size_t)sa);
        float2 vb = *(const float2*)(g + 2 * (size_t)sb);
        z0 += va.x; z1 += va.y;
        y0b += vb.x; y1b += vb.y;
    }
    if (i < s1) {
        int sa = clampN(col[i]);
        float2 va = *(const float2*)(g + 2 * (size_t)sa);
        z0 += va.x; z1 += va.y;
    }
    z0 += y0b; z1 += y1b;
    float ic = 1.0f / fmaxf((float)(s1 - s0), 1.0f);
    z0 = z0 * ic + b2[0] + r[2 * (size_t)n];
    z1 = z1 * ic + b2[1] + r[2 * (size_t)n + 1];
    float d = 1.0f / fmaxf(sqrtf(z0 * z0 + z1 * z1), FEPS);
    float y0 = z0 * d, y1 = z1 * d;
    float m = fmaxf(y0, y1);
    float lg = m + logf(__expf(y0 - m) + __expf(y1 - m));
    out[2 * (size_t)n]     = y0 - lg;
    out[2 * (size_t)n + 1] = y1 - lg;
}

// ---------------------------------------------------------------------------
extern "C" void kernel_launch(void* const* d_in, const int* in_sizes, int n_in,
                              void* d_out, int out_size, void* d_ws, size_t ws_size,
                              hipStream_t stream) {
    // setup_inputs order: x, edge_index, W1_l, b1, W1_r, W2_l, b2, W2_r
    const float* x   = (const float*)d_in[0];
    const int*   ei  = (const int*)d_in[1];
    const float* W1l = (const float*)d_in[2];
    const float* b1  = (const float*)d_in[3];
    const float* W1r = (const float*)d_in[4];
    const float* W2l = (const float*)d_in[5];
    const float* b2  = (const float*)d_in[6];
    const float* W2r = (const float*)d_in[7];

    const int nsb = (NN + 1023) / 1024;          // 98 scan blocks
    const int ncv = (NN * FIN / 8 + 255) / 256;  // convert blocks
    const int ecb = (NE + 255) / 256;            // edge blocks

    const size_t tailWords = (size_t)2 * NN + (NN + 1) + NE + 4 * NN + 128;
    const size_t needB = (size_t)256 * 256 * 4 + (size_t)NN * FIN * 2 +
                         tailWords * 4;
    const size_t needA = needB + (size_t)NN * FIN * 4;   // + fp32 agg

    // host-side constants: graph-safe
    bool pathA = (ws_size >= needA);
    bool pathB = !pathA && (ws_size >= needB);
    bool half  = pathA || pathB;

    char* p = (char*)d_ws;
    __half* Bfh = (__half*)p;             p += (size_t)256 * 256 * 2;
    __half* Bfl = (__half*)p;             p += (size_t)256 * 256 * 2;
    __half* xh = nullptr;
    if (half) { xh = (__half*)p;          p += (size_t)NN * FIN * 2; }
    float* agg = nullptr;
    if (pathA) { agg = (float*)p;         p += (size_t)NN * FIN * 4; }

    int*   cnt  = (int*)p;
    int*   cur  = cnt + NN;
    int*   off  = cur + NN;                      // NN+1
    int*   col  = off + NN + 1;                  // NE
    float* g    = (float*)(col + NE);            // NN*2
    float* r    = g + 2 * (size_t)NN;            // NN*2
    int*   bsum = (int*)(r + 2 * (size_t)NN);    // 128

    hipMemsetAsync(cnt, 0, 2 * (size_t)NN * sizeof(int), stream);

    int cv = half ? ncv : 0;
    setup_kernel<<<256 + cv + ecb, 256, 0, stream>>>(ei, x, W1l, W1r,
                                                     Bfh, Bfl, xh, cnt, cv);
    scan_a_kernel<<<nsb, 1024, 0, stream>>>(cnt, off, bsum);
    scan_b_kernel<<<1, 128, 0, stream>>>(bsum, off, nsb);
    scan_c_kernel<<<nsb, 1024, 0, stream>>>(bsum, off);
    fill_kernel<<<ecb, 256, 0, stream>>>(ei, off, cur, col);

    if (pathA) {
        gather_kernel<<<(NN * 16 + 255) / 256, 256, 0, stream>>>(off, col, xh,
                                                                 agg);
        gemm_mfma_kernel<<<(NN + 63) / 64, 512, 0, stream>>>(agg, x, Bfh, Bfl,
                                                             b1, W2l, W2r, g, r);
    } else if (pathB) {
        layer1_kernel<true><<<(NN + 63) / 64, 1024, 0, stream>>>(
            off, col, x, xh, Bfh, Bfl, b1, W2l, W2r, g, r);
    } else {
        layer1_kernel<false><<<(NN + 63) / 64, 1024, 0, stream>>>(
            off, col, x, xh, Bfh, Bfl, b1, W2l, W2r, g, r);
    }
    finalize_kernel<<<(NN + 255) / 256, 256, 0, stream>>>(off, col, g, r, b2,
                                                          (float*)d_out);
}